// Round 14
// baseline (118.424 us; speedup 1.0000x reference)
//
#include <hip/hip_runtime.h>
#include <stdint.h>

#define N1 8192
#define N2 8192
#define DK 128
#define TAU 0.08f     // repair margin (sim units); ~15 sigma of f16 dot noise
#define BIAS 256.0f   // sim in [-70,70] -> biased keys are positive floats
#define LDR 132       // B-tile LDS row stride in f16 (264 B)

typedef _Float16 half8 __attribute__((ext_vector_type(8)));
typedef _Float16 half4 __attribute__((ext_vector_type(4)));
typedef float floatx4 __attribute__((ext_vector_type(4)));

// Module-scope device scratch (graph-capture safe). Fully rewritten each launch.
__device__ __align__(16) _Float16 g_Af[N1 * DK];        // 2 MB
__device__ __align__(16) _Float16 g_Bf[N2 * DK];        // 2 MB
__device__ __align__(16) float2 g_rowtop2[64 * N1];     // 4 MB [128colgrp][row] tile-owned
__device__ __align__(16) float2 g_coltop2[64 * N2];     // 4 MB [128rowgrp][col]
__device__ int g_nn21[N2];
__device__ int g_col_done;                               // colside completion counter

// ---- biased-float keys (group top2; quant <= 3.9e-3 << TAU) ----
__device__ __forceinline__ float bval(float key) {
    return __uint_as_float(__float_as_uint(key) & 0xFFFFFF80u);
}
__device__ __forceinline__ int bidx(float key) {
    return (int)(__float_as_uint(key) & 127u);
}
__device__ __forceinline__ void push2f(float& t1, float& t2, float p) {
    float m = __builtin_amdgcn_fmed3f(t1, t2, p);
    t1 = fmaxf(t1, p);
    t2 = m;
}
__device__ __forceinline__ void merge2f(float& t1, float& t2, float o1, float o2) {
    float x = fmaxf(t2, o2);
    float m = __builtin_amdgcn_fmed3f(t1, o1, x);
    t1 = fmaxf(t1, o1);
    t2 = m;
}
__device__ __forceinline__ float2 m2(float2 a, float2 b) {
    merge2f(a.x, a.y, b.x, b.y);
    return a;
}
// DPP lane-permute within each 16-lane row (VALU op). R22 lesson: wins on the
// block-critical-path reduce in fix_kernel; loses in sim's row phase. Used in
// fix_kernel only.
#define DPPF(x, ctrl) __int_as_float(__builtin_amdgcn_update_dpp( \
        0, __float_as_int(x), (ctrl), 0xF, 0xF, true))

// ---- exact monotone pack for the repair path ----
__device__ __forceinline__ unsigned mono32(float v) {
    unsigned u = __float_as_uint(v);
    return u ^ ((u & 0x80000000u) ? 0xFFFFFFFFu : 0x80000000u);
}
__device__ __forceinline__ float unmono32(unsigned k) {
    unsigned u = (k & 0x80000000u) ? (k ^ 0x80000000u) : ~k;
    return __uint_as_float(u);
}
__device__ __forceinline__ unsigned long long pack64(float d, unsigned idx) {
    return ((unsigned long long)mono32(d) << 32) | (unsigned)(~idx);
}

// fp32 -> f16 staging kernel (R19: fusing into sim blows per-XCD L2).
// Also resets g_col_done each launch/replay (kernel-boundary visibility).
__global__ __launch_bounds__(256) void convert_kernel(const float* __restrict__ A,
                                                      const float* __restrict__ B) {
    if (blockIdx.x == 0 && threadIdx.x == 0) g_col_done = 0;
    int t = blockIdx.x * blockDim.x + threadIdx.x;
    const int perMat = N1 * (DK / 4);
    int which = (t >= perMat) ? 1 : 0;
    const float* src = which ? B : A;
    _Float16* dst = which ? g_Bf : g_Af;
    int i = which ? t - perMat : t;
    int m = i >> 5;
    int kq = i & 31;
    float4 v = *reinterpret_cast<const float4*>(src + (size_t)m * DK + kq * 4);
    half4 h = {(_Float16)v.x, (_Float16)v.y, (_Float16)v.z, (_Float16)v.w};
    *reinterpret_cast<half4*>(dst + (size_t)m * DK + kq * 4) = h;
}

// 128x128 tile per block, 4 waves. Best-known structure (R30/R32, 111.7us):
// padded-LDS staging, LDS gather-merge row phase (R24), bias-fold + col phase
// pre-barrier (R30), setprio on MFMA cluster (R29), XCD swizzle (R16).
// Occupancy VGPR-bucket-pinned at 4 waves/SIMD for VGPR in (64,128] —
// the 64-reg accumulator makes >4 impossible (R21/R23). Staging-stall attack
// closed (R25 bank conflicts / R27 neutral / R31 spill).
__global__ __launch_bounds__(256) void simf16_kernel() {
    __shared__ union {
        _Float16 Bs[128 * LDR];          // 33792 B (GEMM phase)
        float2 scr[128][34];             // 34816 B (row-merge phase; 272 B rows)
    } sm;
    __shared__ float2 lmerge[2][128];    // 2 KB (col phase only)

    const int tid  = threadIdx.x;
    const int lane = tid & 63;
    const int wave = tid >> 6;
    const int wm = wave >> 1, wn = wave & 1;
    const int fr = lane & 15, q = lane >> 4;

    // XCD swizzle: dispatch-neighbors share ty, clustered tx -> A-panel L2 reuse.
    const int flat = blockIdx.y * 64 + blockIdx.x;
    const int xcd = flat & 7;
    const int j = flat >> 3;
    const int ty = j >> 3;
    const int tx = ((j & 7) << 3) | xcd;
    const int row0 = ty * 128, col0 = tx * 128;

    // ---- stage B tile only (2048 16-B chunks; fully coalesced) ----
#pragma unroll
    for (int i = 0; i < 8; ++i) {
        int f = i * 256 + tid;
        int r = f >> 4, c = f & 15;
        *reinterpret_cast<float4*>(&sm.Bs[r * LDR + c * 8]) =
            *reinterpret_cast<const float4*>(g_Bf + (size_t)(col0 + r) * DK + c * 8);
    }

    floatx4 acc[4][4];
#pragma unroll
    for (int mt = 0; mt < 4; ++mt)
#pragma unroll
        for (int nt = 0; nt < 4; ++nt)
            acc[mt][nt] = (floatx4){0.f, 0.f, 0.f, 0.f};

    const _Float16* Abase = g_Af + (size_t)(row0 + wm * 64 + fr) * DK + q * 8;

    // prefetch ks=0 A fragments (independent of the B staging above)
    half8 af[4], afn[4];
#pragma unroll
    for (int mt = 0; mt < 4; ++mt)
        af[mt] = *reinterpret_cast<const half8*>(Abase + mt * 16 * DK);

    __syncthreads();   // B tile ready

#pragma unroll
    for (int ks = 0; ks < 4; ++ks) {
        if (ks < 3) {
#pragma unroll
            for (int mt = 0; mt < 4; ++mt)
                afn[mt] = *reinterpret_cast<const half8*>(Abase + mt * 16 * DK + (ks + 1) * 32);
        }
        half8 bf[4];
#pragma unroll
        for (int nt = 0; nt < 4; ++nt)
            bf[nt] = *reinterpret_cast<const half8*>(&sm.Bs[(wn * 64 + nt * 16 + fr) * LDR + ks * 32 + q * 8]);
        __builtin_amdgcn_s_setprio(1);
#pragma unroll
        for (int mt = 0; mt < 4; ++mt)
#pragma unroll
            for (int nt = 0; nt < 4; ++nt)
                acc[mt][nt] = __builtin_amdgcn_mfma_f32_16x16x32_f16(af[mt], bf[nt], acc[mt][nt], 0, 0, 0);
        __builtin_amdgcn_s_setprio(0);
        if (ks < 3) {
#pragma unroll
            for (int mt = 0; mt < 4; ++mt)
                af[mt] = afn[mt];
        }
    }

    // ---- fold bias+round into acc in place (register-only; pre-barrier) ----
#pragma unroll
    for (int mt = 0; mt < 4; ++mt)
#pragma unroll
        for (int nt = 0; nt < 4; ++nt)
#pragma unroll
            for (int reg = 0; reg < 4; ++reg)
                acc[mt][nt][reg] = __uint_as_float(
                    __float_as_uint(acc[mt][nt][reg] + BIAS) & 0xFFFFFF80u);

    // ---- col phase (pre-barrier: touches neither Bs nor scr) ----
    // top2 over 128 rows; writes lmerge only.
#pragma unroll
    for (int nt = 0; nt < 4; ++nt) {
        float t1 = 0.f, t2 = 0.f;
#pragma unroll
        for (int mt = 0; mt < 4; ++mt)
#pragma unroll
            for (int reg = 0; reg < 4; ++reg)
                push2f(t1, t2, __uint_as_float(__float_as_uint(acc[mt][nt][reg])
                                               | (unsigned)(wm * 64 + mt * 16 + q * 4 + reg)));
        float o1 = __shfl_xor(t1, 16, 64), o2 = __shfl_xor(t2, 16, 64);
        merge2f(t1, t2, o1, o2);
        o1 = __shfl_xor(t1, 32, 64); o2 = __shfl_xor(t2, 32, 64);
        merge2f(t1, t2, o1, o2);
        if (q == 0) lmerge[wm][wn * 64 + nt * 16 + fr] = make_float2(t1, t2);
    }

    __syncthreads();   // all K-loops done (Bs free) + all lmerge writes landed

    // ---- row phase, step 1: lane-local nt-partial -> scratch ----
    // scr[row][wn*16+fr] = top2 over the 4 cols {wn*64 + nt*16 + fr}
#pragma unroll
    for (int mt = 0; mt < 4; ++mt) {
#pragma unroll
        for (int reg = 0; reg < 4; ++reg) {
            float t1 = 0.f, t2 = 0.f;
#pragma unroll
            for (int nt = 0; nt < 4; ++nt)
                push2f(t1, t2, __uint_as_float(__float_as_uint(acc[mt][nt][reg])
                                               | (unsigned)(wn * 64 + nt * 16 + fr)));
            sm.scr[wm * 64 + mt * 16 + q * 4 + reg][wn * 16 + fr] = make_float2(t1, t2);
        }
    }

    // ---- col final merge (overlaps the scr ds_writes above) ----
    if (tid < 128) {
        float2 a = lmerge[0][tid], b = lmerge[1][tid];
        merge2f(a.x, a.y, b.x, b.y);
        g_coltop2[(size_t)ty * N2 + col0 + tid] = a;
    }
    __syncthreads();   // scr complete before step2 reads

    // ---- row phase, step 2: 2 threads/row tree-merge 16 entries + 1 shfl ----
    {
        const int row = tid >> 1, h = tid & 1;
        const float4* p = reinterpret_cast<const float4*>(&sm.scr[row][h * 16]);
        float4 v0 = p[0], v1 = p[1], v2 = p[2], v3 = p[3];
        float4 v4 = p[4], v5 = p[5], v6 = p[6], v7 = p[7];
        float2 r0 = m2(make_float2(v0.x, v0.y), make_float2(v0.z, v0.w));
        float2 r1 = m2(make_float2(v1.x, v1.y), make_float2(v1.z, v1.w));
        float2 r2 = m2(make_float2(v2.x, v2.y), make_float2(v2.z, v2.w));
        float2 r3 = m2(make_float2(v3.x, v3.y), make_float2(v3.z, v3.w));
        float2 r4 = m2(make_float2(v4.x, v4.y), make_float2(v4.z, v4.w));
        float2 r5 = m2(make_float2(v5.x, v5.y), make_float2(v5.z, v5.w));
        float2 r6 = m2(make_float2(v6.x, v6.y), make_float2(v6.z, v6.w));
        float2 r7 = m2(make_float2(v7.x, v7.y), make_float2(v7.z, v7.w));
        r0 = m2(r0, r1); r2 = m2(r2, r3); r4 = m2(r4, r5); r6 = m2(r6, r7);
        r0 = m2(r0, r2); r4 = m2(r4, r6);
        r0 = m2(r0, r4);
        float o1 = __shfl_xor(r0.x, 1, 64), o2 = __shfl_xor(r0.y, 1, 64);
        merge2f(r0.x, r0.y, o1, o2);
        if (h == 0) g_rowtop2[(size_t)tx * N1 + row0 + row] = r0;
    }
}

// 1024 blocks: 0..511 repair cols -> g_nn21; 512..1023 repair rows + exact
// scores + MUTUAL (R33). Candidates within TAU of approx max get the fp32
// SEQUENTIAL k-ascending fmaf chain (bitwise reference rounding, R6-proven).
// R33 mutual fusion WITHOUT fences (R28 lesson: per-block __threadfence =
// 1024 L2 writebacks = +84us): colside publishes nn21 via agent-scope
// RELAXED atomic stores (coherence-point ops, no wbl2) + counter add after
// vmcnt drain; rowside keeps nn12 LOCAL (mutual was its only reader), spins
// on the counter (deadlock-safe: VGPR 32/LDS 9.7KB -> 2048 co-resident slots
// >= 1024 blocks; colside never waits), then 16 agent loads of nn21[m].
__global__ __launch_bounds__(256) void fix_kernel(const float* __restrict__ A,
                                                  const float* __restrict__ B,
                                                  float* __restrict__ out) {
    __shared__ float2 tile[64 * 16];          // 8 KB
    __shared__ unsigned long long slot[16];
    __shared__ int cand[256];
    __shared__ int cand_cnt;

    const int tid = threadIdx.x;
    const bool rowside = blockIdx.x >= 512;
    const int base0 = (blockIdx.x & 511) * 16;
    const float2* top2 = rowside ? g_rowtop2 : g_coltop2;

#pragma unroll
    for (int i = 0; i < 4; ++i) {
        int idx = i * 256 + tid;              // 0..1023
        int grp = idx >> 4, c = idx & 15;
        tile[grp * 16 + c] = top2[(size_t)grp * N1 + base0 + c];
    }
    if (tid < 16) slot[tid] = 0ULL;
    if (tid == 0) cand_cnt = 0;
    __syncthreads();

    const int c = tid >> 4, j = tid & 15;     // 16 threads per row/col
    float mx = 0.f;                           // biased domain, all keys > 0
#pragma unroll
    for (int s = 0; s < 4; ++s)
        mx = fmaxf(mx, tile[(j * 4 + s) * 16 + c].x);
    // 16-lane max reduce on the VALU pipe (DPP rotations; max is idempotent)
    mx = fmaxf(mx, DPPF(mx, 0xB1));
    mx = fmaxf(mx, DPPF(mx, 0x4E));
    mx = fmaxf(mx, DPPF(mx, 0x124));
    mx = fmaxf(mx, DPPF(mx, 0x128));
    const float thr = bval(mx) - TAU;
#pragma unroll
    for (int s = 0; s < 4; ++s) {
        int grp = j * 4 + s;
        float2 e = tile[grp * 16 + c];
        if (bval(e.x) >= thr) {
            int o = grp * 128 + bidx(e.x);
            int si = atomicAdd(&cand_cnt, 1);
            if (si < 256) cand[si] = (c << 16) | o;
        }
        if (bval(e.y) >= thr) {
            int o = grp * 128 + bidx(e.y);
            int si = atomicAdd(&cand_cnt, 1);
            if (si < 256) cand[si] = (c << 16) | o;
        }
    }
    __syncthreads();

    const int nc = min(cand_cnt, 256);
    for (int i = tid; i < nc; i += 256) {
        int pc = cand[i];
        int cl = pc >> 16, other = pc & 0xFFFF;
        const float* ar = rowside ? (A + (size_t)(base0 + cl) * DK) : (A + (size_t)other * DK);
        const float* br = rowside ? (B + (size_t)other * DK) : (B + (size_t)(base0 + cl) * DK);
        float d = 0.0f;
#pragma unroll
        for (int k4 = 0; k4 < DK / 4; ++k4) {
            float4 a = *reinterpret_cast<const float4*>(ar + k4 * 4);
            float4 b = *reinterpret_cast<const float4*>(br + k4 * 4);
            d = fmaf(a.x, b.x, d);
            d = fmaf(a.y, b.y, d);
            d = fmaf(a.z, b.z, d);
            d = fmaf(a.w, b.w, d);
        }
        atomicMax(&slot[cl], pack64(d, (unsigned)other));
    }
    __syncthreads();

    if (!rowside) {
        // ---- colside: publish nn21 at coherence point, then count in ----
        if (tid < 16) {
            unsigned long long p = slot[tid];
            __hip_atomic_store(&g_nn21[base0 + tid], (int)(~(unsigned)p),
                               __ATOMIC_RELAXED, __HIP_MEMORY_SCOPE_AGENT);
        }
        __syncthreads();   // drains vmcnt: the 16 stores are complete
        if (tid == 0)
            __hip_atomic_fetch_add(&g_col_done, 1,
                                   __ATOMIC_RELAXED, __HIP_MEMORY_SCOPE_AGENT);
    } else {
        // ---- rowside: exact score + local nn12, wait for colside, mutual ----
        int m_local = 0;
        if (tid < 16) {
            unsigned long long p = slot[tid];
            m_local = (int)(~(unsigned)p);
            out[N1 + base0 + tid] = unmono32((unsigned)(p >> 32));   // exact score
        }
        if (tid == 0) {
            while (__hip_atomic_load(&g_col_done, __ATOMIC_RELAXED,
                                     __HIP_MEMORY_SCOPE_AGENT) < 512)
                __builtin_amdgcn_s_sleep(8);
        }
        __syncthreads();   // col_done==512: all nn21 stores at coherence point
        if (tid < 16) {
            int v21 = __hip_atomic_load(&g_nn21[m_local], __ATOMIC_RELAXED,
                                        __HIP_MEMORY_SCOPE_AGENT);
            int idx = base0 + tid;
            out[idx] = (float)((v21 == idx) ? m_local : -1);   // matches0
        }
    }
}

extern "C" void kernel_launch(void* const* d_in, const int* in_sizes, int n_in,
                              void* d_out, int out_size, void* d_ws, size_t ws_size,
                              hipStream_t stream) {
    const float* A = (const float*)d_in[0];   // desc1 [8192,128] f32
    const float* B = (const float*)d_in[1];   // desc2 [8192,128] f32
    float* out = (float*)d_out;               // [0:8192]=matches, [8192:16384]=scores

    convert_kernel<<<2 * N1 * (DK / 4) / 256, 256, 0, stream>>>(A, B);
    dim3 grid(64, 64);
    simf16_kernel<<<grid, 256, 0, stream>>>();
    fix_kernel<<<1024, 256, 0, stream>>>(A, B, out);   // mutual fused (R33)
}

// Round 15
// 111.363 us; speedup vs baseline: 1.0634x; 1.0634x over previous
//
#include <hip/hip_runtime.h>
#include <stdint.h>

#define N1 8192
#define N2 8192
#define DK 128
#define TAU 0.08f     // repair margin (sim units); ~15 sigma of f16 dot noise
#define BIAS 256.0f   // sim in [-70,70] -> biased keys are positive floats
#define LDR 132       // B-tile LDS row stride in f16 (264 B)

typedef _Float16 half8 __attribute__((ext_vector_type(8)));
typedef _Float16 half4 __attribute__((ext_vector_type(4)));
typedef float floatx4 __attribute__((ext_vector_type(4)));

// Module-scope device scratch (graph-capture safe). Fully rewritten each launch.
__device__ __align__(16) _Float16 g_Af[N1 * DK];        // 2 MB
__device__ __align__(16) _Float16 g_Bf[N2 * DK];        // 2 MB
__device__ __align__(16) float2 g_rowtop2[64 * N1];     // 4 MB [128colgrp][row] tile-owned
__device__ __align__(16) float2 g_coltop2[64 * N2];     // 4 MB [128rowgrp][col]
__device__ int g_nn12[N1];
__device__ int g_nn21[N2];

// ---- biased-float keys (group top2; quant <= 3.9e-3 << TAU) ----
__device__ __forceinline__ float bval(float key) {
    return __uint_as_float(__float_as_uint(key) & 0xFFFFFF80u);
}
__device__ __forceinline__ int bidx(float key) {
    return (int)(__float_as_uint(key) & 127u);
}
__device__ __forceinline__ void push2f(float& t1, float& t2, float p) {
    float m = __builtin_amdgcn_fmed3f(t1, t2, p);
    t1 = fmaxf(t1, p);
    t2 = m;
}
__device__ __forceinline__ void merge2f(float& t1, float& t2, float o1, float o2) {
    float x = fmaxf(t2, o2);
    float m = __builtin_amdgcn_fmed3f(t1, o1, x);
    t1 = fmaxf(t1, o1);
    t2 = m;
}
__device__ __forceinline__ float2 m2(float2 a, float2 b) {
    merge2f(a.x, a.y, b.x, b.y);
    return a;
}
// DPP lane-permute within each 16-lane row (VALU op). R22 lesson: wins on the
// block-critical-path reduce in fix_kernel; loses in sim's row phase. Used in
// fix_kernel only.
#define DPPF(x, ctrl) __int_as_float(__builtin_amdgcn_update_dpp( \
        0, __float_as_int(x), (ctrl), 0xF, 0xF, true))

// ---- exact monotone pack for the repair path ----
__device__ __forceinline__ unsigned mono32(float v) {
    unsigned u = __float_as_uint(v);
    return u ^ ((u & 0x80000000u) ? 0xFFFFFFFFu : 0x80000000u);
}
__device__ __forceinline__ float unmono32(unsigned k) {
    unsigned u = (k & 0x80000000u) ? (k ^ 0x80000000u) : ~k;
    return __uint_as_float(u);
}
__device__ __forceinline__ unsigned long long pack64(float d, unsigned idx) {
    return ((unsigned long long)mono32(d) << 32) | (unsigned)(~idx);
}

// fp32 -> f16 staging kernel (R19: fusing into sim blows per-XCD L2).
__global__ __launch_bounds__(256) void convert_kernel(const float* __restrict__ A,
                                                      const float* __restrict__ B) {
    int t = blockIdx.x * blockDim.x + threadIdx.x;
    const int perMat = N1 * (DK / 4);
    int which = (t >= perMat) ? 1 : 0;
    const float* src = which ? B : A;
    _Float16* dst = which ? g_Bf : g_Af;
    int i = which ? t - perMat : t;
    int m = i >> 5;
    int kq = i & 31;
    float4 v = *reinterpret_cast<const float4*>(src + (size_t)m * DK + kq * 4);
    half4 h = {(_Float16)v.x, (_Float16)v.y, (_Float16)v.z, (_Float16)v.w};
    *reinterpret_cast<half4*>(dst + (size_t)m * DK + kq * 4) = h;
}

// 128x128 tile per block, 4 waves. R34 = R32/R30 exact revert — the session's
// best-known state (111.4us). Win ledger: R24 LDS gather-merge row phase
// (-8us), R29 setprio on MFMA (-4us), R30 pre-barrier bias-fold+col phase,
// 3->2 barriers (-5us). Closed levers (counter-backed): occupancy pinned at
// 4 waves/SIMD by the 64-reg accumulator (R21/R23 VGPR bucket; clamping
// spills); staging stall (R25 async-DMA doubled bank conflicts, R27 neutral,
// R31 reg-prefetch spilled 128MB); DPP in sim row phase (R22 regression);
// launch fusion (R28 fence storm +78us, R33 spin serialization +7us).
// Residual: latency-bound at MfmaUtil 13 / VALUBusy 56 — serial merge-chain
// dependency floor for this structure, not a HW roofline.
__global__ __launch_bounds__(256) void simf16_kernel() {
    __shared__ union {
        _Float16 Bs[128 * LDR];          // 33792 B (GEMM phase)
        float2 scr[128][34];             // 34816 B (row-merge phase; 272 B rows)
    } sm;
    __shared__ float2 lmerge[2][128];    // 2 KB (col phase only)

    const int tid  = threadIdx.x;
    const int lane = tid & 63;
    const int wave = tid >> 6;
    const int wm = wave >> 1, wn = wave & 1;
    const int fr = lane & 15, q = lane >> 4;

    // XCD swizzle: dispatch-neighbors share ty, clustered tx -> A-panel L2 reuse.
    const int flat = blockIdx.y * 64 + blockIdx.x;
    const int xcd = flat & 7;
    const int j = flat >> 3;
    const int ty = j >> 3;
    const int tx = ((j & 7) << 3) | xcd;
    const int row0 = ty * 128, col0 = tx * 128;

    // ---- stage B tile only (2048 16-B chunks; fully coalesced) ----
#pragma unroll
    for (int i = 0; i < 8; ++i) {
        int f = i * 256 + tid;
        int r = f >> 4, c = f & 15;
        *reinterpret_cast<float4*>(&sm.Bs[r * LDR + c * 8]) =
            *reinterpret_cast<const float4*>(g_Bf + (size_t)(col0 + r) * DK + c * 8);
    }

    floatx4 acc[4][4];
#pragma unroll
    for (int mt = 0; mt < 4; ++mt)
#pragma unroll
        for (int nt = 0; nt < 4; ++nt)
            acc[mt][nt] = (floatx4){0.f, 0.f, 0.f, 0.f};

    const _Float16* Abase = g_Af + (size_t)(row0 + wm * 64 + fr) * DK + q * 8;

    // prefetch ks=0 A fragments (independent of the B staging above)
    half8 af[4], afn[4];
#pragma unroll
    for (int mt = 0; mt < 4; ++mt)
        af[mt] = *reinterpret_cast<const half8*>(Abase + mt * 16 * DK);

    __syncthreads();   // B tile ready

#pragma unroll
    for (int ks = 0; ks < 4; ++ks) {
        if (ks < 3) {
#pragma unroll
            for (int mt = 0; mt < 4; ++mt)
                afn[mt] = *reinterpret_cast<const half8*>(Abase + mt * 16 * DK + (ks + 1) * 32);
        }
        half8 bf[4];
#pragma unroll
        for (int nt = 0; nt < 4; ++nt)
            bf[nt] = *reinterpret_cast<const half8*>(&sm.Bs[(wn * 64 + nt * 16 + fr) * LDR + ks * 32 + q * 8]);
        __builtin_amdgcn_s_setprio(1);
#pragma unroll
        for (int mt = 0; mt < 4; ++mt)
#pragma unroll
            for (int nt = 0; nt < 4; ++nt)
                acc[mt][nt] = __builtin_amdgcn_mfma_f32_16x16x32_f16(af[mt], bf[nt], acc[mt][nt], 0, 0, 0);
        __builtin_amdgcn_s_setprio(0);
        if (ks < 3) {
#pragma unroll
            for (int mt = 0; mt < 4; ++mt)
                af[mt] = afn[mt];
        }
    }

    // ---- fold bias+round into acc in place (register-only; pre-barrier) ----
#pragma unroll
    for (int mt = 0; mt < 4; ++mt)
#pragma unroll
        for (int nt = 0; nt < 4; ++nt)
#pragma unroll
            for (int reg = 0; reg < 4; ++reg)
                acc[mt][nt][reg] = __uint_as_float(
                    __float_as_uint(acc[mt][nt][reg] + BIAS) & 0xFFFFFF80u);

    // ---- col phase (pre-barrier: touches neither Bs nor scr) ----
    // top2 over 128 rows; writes lmerge only.
#pragma unroll
    for (int nt = 0; nt < 4; ++nt) {
        float t1 = 0.f, t2 = 0.f;
#pragma unroll
        for (int mt = 0; mt < 4; ++mt)
#pragma unroll
            for (int reg = 0; reg < 4; ++reg)
                push2f(t1, t2, __uint_as_float(__float_as_uint(acc[mt][nt][reg])
                                               | (unsigned)(wm * 64 + mt * 16 + q * 4 + reg)));
        float o1 = __shfl_xor(t1, 16, 64), o2 = __shfl_xor(t2, 16, 64);
        merge2f(t1, t2, o1, o2);
        o1 = __shfl_xor(t1, 32, 64); o2 = __shfl_xor(t2, 32, 64);
        merge2f(t1, t2, o1, o2);
        if (q == 0) lmerge[wm][wn * 64 + nt * 16 + fr] = make_float2(t1, t2);
    }

    __syncthreads();   // all K-loops done (Bs free) + all lmerge writes landed

    // ---- row phase, step 1: lane-local nt-partial -> scratch ----
    // scr[row][wn*16+fr] = top2 over the 4 cols {wn*64 + nt*16 + fr}
#pragma unroll
    for (int mt = 0; mt < 4; ++mt) {
#pragma unroll
        for (int reg = 0; reg < 4; ++reg) {
            float t1 = 0.f, t2 = 0.f;
#pragma unroll
            for (int nt = 0; nt < 4; ++nt)
                push2f(t1, t2, __uint_as_float(__float_as_uint(acc[mt][nt][reg])
                                               | (unsigned)(wn * 64 + nt * 16 + fr)));
            sm.scr[wm * 64 + mt * 16 + q * 4 + reg][wn * 16 + fr] = make_float2(t1, t2);
        }
    }

    // ---- col final merge (overlaps the scr ds_writes above) ----
    if (tid < 128) {
        float2 a = lmerge[0][tid], b = lmerge[1][tid];
        merge2f(a.x, a.y, b.x, b.y);
        g_coltop2[(size_t)ty * N2 + col0 + tid] = a;
    }
    __syncthreads();   // scr complete before step2 reads

    // ---- row phase, step 2: 2 threads/row tree-merge 16 entries + 1 shfl ----
    {
        const int row = tid >> 1, h = tid & 1;
        const float4* p = reinterpret_cast<const float4*>(&sm.scr[row][h * 16]);
        float4 v0 = p[0], v1 = p[1], v2 = p[2], v3 = p[3];
        float4 v4 = p[4], v5 = p[5], v6 = p[6], v7 = p[7];
        float2 r0 = m2(make_float2(v0.x, v0.y), make_float2(v0.z, v0.w));
        float2 r1 = m2(make_float2(v1.x, v1.y), make_float2(v1.z, v1.w));
        float2 r2 = m2(make_float2(v2.x, v2.y), make_float2(v2.z, v2.w));
        float2 r3 = m2(make_float2(v3.x, v3.y), make_float2(v3.z, v3.w));
        float2 r4 = m2(make_float2(v4.x, v4.y), make_float2(v4.z, v4.w));
        float2 r5 = m2(make_float2(v5.x, v5.y), make_float2(v5.z, v5.w));
        float2 r6 = m2(make_float2(v6.x, v6.y), make_float2(v6.z, v6.w));
        float2 r7 = m2(make_float2(v7.x, v7.y), make_float2(v7.z, v7.w));
        r0 = m2(r0, r1); r2 = m2(r2, r3); r4 = m2(r4, r5); r6 = m2(r6, r7);
        r0 = m2(r0, r2); r4 = m2(r4, r6);
        r0 = m2(r0, r4);
        float o1 = __shfl_xor(r0.x, 1, 64), o2 = __shfl_xor(r0.y, 1, 64);
        merge2f(r0.x, r0.y, o1, o2);
        if (h == 0) g_rowtop2[(size_t)tx * N1 + row0 + row] = r0;
    }
}

// 1024 blocks: 0..511 repair cols (g_nn21), 512..1023 repair rows (g_nn12 +
// exact scores). Candidates within TAU of approx max get the fp32 SEQUENTIAL
// k-ascending fmaf chain (bitwise reference rounding, R6-proven).
__global__ __launch_bounds__(256) void fix_kernel(const float* __restrict__ A,
                                                  const float* __restrict__ B,
                                                  float* __restrict__ out) {
    __shared__ float2 tile[64 * 16];          // 8 KB
    __shared__ unsigned long long slot[16];
    __shared__ int cand[256];
    __shared__ int cand_cnt;

    const int tid = threadIdx.x;
    const bool rowside = blockIdx.x >= 512;
    const int base0 = (blockIdx.x & 511) * 16;
    const float2* top2 = rowside ? g_rowtop2 : g_coltop2;

#pragma unroll
    for (int i = 0; i < 4; ++i) {
        int idx = i * 256 + tid;              // 0..1023
        int grp = idx >> 4, c = idx & 15;
        tile[grp * 16 + c] = top2[(size_t)grp * N1 + base0 + c];
    }
    if (tid < 16) slot[tid] = 0ULL;
    if (tid == 0) cand_cnt = 0;
    __syncthreads();

    const int c = tid >> 4, j = tid & 15;     // 16 threads per row/col
    float mx = 0.f;                           // biased domain, all keys > 0
#pragma unroll
    for (int s = 0; s < 4; ++s)
        mx = fmaxf(mx, tile[(j * 4 + s) * 16 + c].x);
    // 16-lane max reduce on the VALU pipe (DPP rotations; max is idempotent)
    mx = fmaxf(mx, DPPF(mx, 0xB1));
    mx = fmaxf(mx, DPPF(mx, 0x4E));
    mx = fmaxf(mx, DPPF(mx, 0x124));
    mx = fmaxf(mx, DPPF(mx, 0x128));
    const float thr = bval(mx) - TAU;
#pragma unroll
    for (int s = 0; s < 4; ++s) {
        int grp = j * 4 + s;
        float2 e = tile[grp * 16 + c];
        if (bval(e.x) >= thr) {
            int o = grp * 128 + bidx(e.x);
            int si = atomicAdd(&cand_cnt, 1);
            if (si < 256) cand[si] = (c << 16) | o;
        }
        if (bval(e.y) >= thr) {
            int o = grp * 128 + bidx(e.y);
            int si = atomicAdd(&cand_cnt, 1);
            if (si < 256) cand[si] = (c << 16) | o;
        }
    }
    __syncthreads();

    const int nc = min(cand_cnt, 256);
    for (int i = tid; i < nc; i += 256) {
        int pc = cand[i];
        int cl = pc >> 16, other = pc & 0xFFFF;
        const float* ar = rowside ? (A + (size_t)(base0 + cl) * DK) : (A + (size_t)other * DK);
        const float* br = rowside ? (B + (size_t)other * DK) : (B + (size_t)(base0 + cl) * DK);
        float d = 0.0f;
#pragma unroll
        for (int k4 = 0; k4 < DK / 4; ++k4) {
            float4 a = *reinterpret_cast<const float4*>(ar + k4 * 4);
            float4 b = *reinterpret_cast<const float4*>(br + k4 * 4);
            d = fmaf(a.x, b.x, d);
            d = fmaf(a.y, b.y, d);
            d = fmaf(a.z, b.z, d);
            d = fmaf(a.w, b.w, d);
        }
        atomicMax(&slot[cl], pack64(d, (unsigned)other));
    }
    __syncthreads();

    if (tid < 16) {
        unsigned long long p = slot[tid];
        int idx = base0 + tid;
        if (rowside) {
            g_nn12[idx] = (int)(~(unsigned)p);
            out[N1 + idx] = unmono32((unsigned)(p >> 32));   // exact score
        } else {
            g_nn21[idx] = (int)(~(unsigned)p);
        }
    }
}

// Tiny mutual pass (32 blocks): both nn arrays complete after fix_kernel.
// R28/R33 lessons: fusing this into fix costs MORE than the launch — fence
// storm (+78us) or colside-spin serialization (+7us). Keep the launch.
__global__ __launch_bounds__(256) void mutual_kernel(float* __restrict__ out) {
    int i = blockIdx.x * blockDim.x + threadIdx.x;
    if (i < N1) {
        int m = g_nn12[i];
        out[i] = (float)((g_nn21[m] == i) ? m : -1);   // matches0
    }
}

extern "C" void kernel_launch(void* const* d_in, const int* in_sizes, int n_in,
                              void* d_out, int out_size, void* d_ws, size_t ws_size,
                              hipStream_t stream) {
    const float* A = (const float*)d_in[0];   // desc1 [8192,128] f32
    const float* B = (const float*)d_in[1];   // desc2 [8192,128] f32
    float* out = (float*)d_out;               // [0:8192]=matches, [8192:16384]=scores

    convert_kernel<<<2 * N1 * (DK / 4) / 256, 256, 0, stream>>>(A, B);
    dim3 grid(64, 64);
    simf16_kernel<<<grid, 256, 0, stream>>>();
    fix_kernel<<<1024, 256, 0, stream>>>(A, B, out);
    mutual_kernel<<<N1 / 256, 256, 0, stream>>>(out);
}